// Round 9
// baseline (1199.506 us; speedup 1.0000x reference)
//
#include <hip/hip_runtime.h>
#include <hip/hip_bf16.h>
#include <math.h>
#include <stdint.h>

// Problem constants
#define B_ 4
#define VH_ 130
#define VL_ 120
#define EP_ 256
#define R_ 506           // VH+VL+EP
#define RP_ 512          // padded R for transposed K/V layouts
#define DIN_ 256
#define DEP_ 128
#define D_ 512
#define H_ 16
#define NL_ 8
#define HID_ 2048

#define MODE_STORE 0
#define MODE_ADD_BIAS 1

typedef _Float16 half8 __attribute__((ext_vector_type(8)));
typedef float f32x4 __attribute__((ext_vector_type(4)));

// async global->LDS 16B copy (width literal)
#define ASYNC16(ldsdst, gsrc)                                                  \
  __builtin_amdgcn_global_load_lds(                                            \
      (const __attribute__((address_space(1))) unsigned int*)(gsrc),           \
      (__attribute__((address_space(3))) unsigned int*)(ldsdst), 16, 0, 0)

// ---------------------------------------------------------------------------
// fp16 MFMA GEMM, BM=128 BN=64, 4-deep pipeline, fused SwiGLU (dual-B).
// ghalf[m,n] = f16( silu(A@Wa^T) * (A@Wv^T) ), N=HID. (validated round 5)
// ---------------------------------------------------------------------------
__global__ __launch_bounds__(256) void gemm16sw_kernel(
    const _Float16* __restrict__ A, const _Float16* __restrict__ Wa,
    const _Float16* __restrict__ Wv, _Float16* __restrict__ Gh,
    int M, int K) {
  __shared__ _Float16 Al[4][4096];
  __shared__ _Float16 Ba[4][2048];
  __shared__ _Float16 Bv[4][2048];

  const int t = threadIdx.x;
  const int nbm = (M + 127) >> 7;
  const int nwg = gridDim.x;
  int bid = blockIdx.x;
  if ((nwg & 7) == 0) {
    int q = nwg >> 3;
    bid = (bid & 7) * q + (bid >> 3);
  }
  const int bm = bid % nbm, bn = bid / nbm;
  const int lane = t & 63;
  const int w = t >> 6;
  const int wm = w >> 1, wn = w & 1;

  const int r0 = t >> 2;
  const int cp = t & 3;
  const int gc = cp ^ ((r0 >> 1) & 3);
  int gr0 = bm * 128 + r0;       if (gr0 >= M) gr0 = M - 1;
  int gr1 = bm * 128 + 64 + r0;  if (gr1 >= M) gr1 = M - 1;
  const int gcol = bn * 64 + r0;  // N=2048 exact
  const _Float16* pA0 = A + (size_t)gr0 * K + gc * 8;
  const _Float16* pA1 = A + (size_t)gr1 * K + gc * 8;
  const _Float16* pBa = Wa + (size_t)gcol * K + gc * 8;
  const _Float16* pBv = Wv + (size_t)gcol * K + gc * 8;

#define STAGE(buf, kt)                                                         \
  do {                                                                         \
    ASYNC16(&Al[buf][t * 8], pA0 + (size_t)(kt) * 32);                         \
    ASYNC16(&Al[buf][2048 + t * 8], pA1 + (size_t)(kt) * 32);                  \
    ASYNC16(&Ba[buf][t * 8], pBa + (size_t)(kt) * 32);                         \
    ASYNC16(&Bv[buf][t * 8], pBv + (size_t)(kt) * 32);                         \
  } while (0)

  f32x4 aca[4][2], acv[4][2];
#pragma unroll
  for (int i = 0; i < 4; i++)
#pragma unroll
    for (int j = 0; j < 2; j++) {
      aca[i][j] = (f32x4){0.f, 0.f, 0.f, 0.f};
      acv[i][j] = (f32x4){0.f, 0.f, 0.f, 0.f};
    }

  const int nt = K >> 5;
  STAGE(0, 0); STAGE(1, 1); STAGE(2, 2);

  const int rl = lane & 15;
  const int ca = (lane >> 4) ^ ((rl >> 1) & 3);
  for (int kt = 0; kt < nt; ++kt) {
    if (kt < nt - 2)       asm volatile("s_waitcnt vmcnt(8)" ::: "memory");
    else if (kt == nt - 2) asm volatile("s_waitcnt vmcnt(4)" ::: "memory");
    else                   asm volatile("s_waitcnt vmcnt(0)" ::: "memory");
    __builtin_amdgcn_s_barrier();
    const int buf = kt & 3;
    const _Float16* Ab  = &Al[buf][(wm * 64 + rl) * 32 + ca * 8];
    const _Float16* Bab = &Ba[buf][(wn * 32 + rl) * 32 + ca * 8];
    const _Float16* Bvb = &Bv[buf][(wn * 32 + rl) * 32 + ca * 8];
    half8 af[4], bfa[2], bfv[2];
#pragma unroll
    for (int i = 0; i < 4; i++) af[i] = *(const half8*)(Ab + i * 512);
#pragma unroll
    for (int j = 0; j < 2; j++) {
      bfa[j] = *(const half8*)(Bab + j * 512);
      bfv[j] = *(const half8*)(Bvb + j * 512);
    }
#pragma unroll
    for (int i = 0; i < 4; i++)
#pragma unroll
      for (int j = 0; j < 2; j++) {
        aca[i][j] = __builtin_amdgcn_mfma_f32_16x16x32_f16(af[i], bfa[j],
                                                           aca[i][j], 0, 0, 0);
        acv[i][j] = __builtin_amdgcn_mfma_f32_16x16x32_f16(af[i], bfv[j],
                                                           acv[i][j], 0, 0, 0);
      }
    if (kt + 3 < nt) STAGE((kt + 3) & 3, kt + 3);
  }
#undef STAGE

  const int rb = bm * 128 + wm * 64 + ((lane >> 4) << 2);
  const int cb = bn * 64 + wn * 32 + (lane & 15);
#pragma unroll
  for (int i = 0; i < 4; i++) {
#pragma unroll
    for (int j = 0; j < 2; j++) {
      int col = cb + j * 16;
#pragma unroll
      for (int q = 0; q < 4; q++) {
        int row = rb + i * 16 + q;
        if (row >= M) continue;
        float a = aca[i][j][q];
        float v = acv[i][j][q];
        Gh[(size_t)row * HID_ + col] = (_Float16)((a / (1.f + expf(-a))) * v);
      }
    }
  }
}

// ---------------------------------------------------------------------------
// fp16 MFMA GEMM, BM=64 BN=64, 4-deep pipeline, C-row-remap + optional fused
// positional encoding. Waves 2x2 of 32x32. LDS 32KB.
// ---------------------------------------------------------------------------
__global__ __launch_bounds__(256) void gemm16b_kernel(
    const _Float16* __restrict__ A, const _Float16* __restrict__ W,
    float* __restrict__ C, const float* __restrict__ bias,
    int M, int N, int K, int mode, int crpb, int cR, int cbase, int pe) {
  __shared__ _Float16 Al[4][2048];
  __shared__ _Float16 Bl[4][2048];

  const int t = threadIdx.x;
  const int nbm = (M + 63) >> 6;
  const int nwg = gridDim.x;
  int bid = blockIdx.x;
  if ((nwg & 7) == 0) {
    int q = nwg >> 3;
    bid = (bid & 7) * q + (bid >> 3);
  }
  const int bm = bid % nbm, bn = bid / nbm;
  const int lane = t & 63;
  const int w = t >> 6;
  const int wm = w >> 1, wn = w & 1;

  const int r0 = t >> 2;
  const int cp = t & 3;
  const int gc = cp ^ ((r0 >> 1) & 3);
  int gr = bm * 64 + r0;    if (gr >= M) gr = M - 1;
  int gcol = bn * 64 + r0;  if (gcol >= N) gcol = N - 1;
  const _Float16* pA = A + (size_t)gr * K + gc * 8;
  const _Float16* pB = W + (size_t)gcol * K + gc * 8;

#define STAGE(buf, kt)                                                         \
  do {                                                                         \
    ASYNC16(&Al[buf][t * 8], pA + (size_t)(kt) * 32);                          \
    ASYNC16(&Bl[buf][t * 8], pB + (size_t)(kt) * 32);                          \
  } while (0)

  f32x4 acc[2][2];
#pragma unroll
  for (int i = 0; i < 2; i++)
#pragma unroll
    for (int j = 0; j < 2; j++) acc[i][j] = (f32x4){0.f, 0.f, 0.f, 0.f};

  const int nt = K >> 5;  // >= 4 at all call sites
  STAGE(0, 0); STAGE(1, 1); STAGE(2, 2);

  const int rl = lane & 15;
  const int ca = (lane >> 4) ^ ((rl >> 1) & 3);
  for (int kt = 0; kt < nt; ++kt) {
    if (kt < nt - 2)       asm volatile("s_waitcnt vmcnt(4)" ::: "memory");
    else if (kt == nt - 2) asm volatile("s_waitcnt vmcnt(2)" ::: "memory");
    else                   asm volatile("s_waitcnt vmcnt(0)" ::: "memory");
    __builtin_amdgcn_s_barrier();
    const int buf = kt & 3;
    half8 af[2], bf[2];
#pragma unroll
    for (int i = 0; i < 2; i++)
      af[i] = *(const half8*)&Al[buf][(wm * 32 + i * 16 + rl) * 32 + ca * 8];
#pragma unroll
    for (int j = 0; j < 2; j++)
      bf[j] = *(const half8*)&Bl[buf][(wn * 32 + j * 16 + rl) * 32 + ca * 8];
#pragma unroll
    for (int i = 0; i < 2; i++)
#pragma unroll
      for (int j = 0; j < 2; j++)
        acc[i][j] = __builtin_amdgcn_mfma_f32_16x16x32_f16(af[i], bf[j],
                                                           acc[i][j], 0, 0, 0);
    if (kt + 3 < nt) STAGE((kt + 3) & 3, kt + 3);
  }
#undef STAGE

  const float PEK = -0.02703623196464017f;  // -2*ln(1000)/511
  const int rb = bm * 64 + wm * 32 + ((lane >> 4) << 2);
  const int cb = bn * 64 + wn * 32 + (lane & 15);
#pragma unroll
  for (int i = 0; i < 2; i++) {
#pragma unroll
    for (int j = 0; j < 2; j++) {
      int col = cb + j * 16;
      if (col >= N) continue;
#pragma unroll
      for (int q = 0; q < 4; q++) {
        int row = rb + i * 16 + q;
        if (row >= M) continue;
        int crow = (row / crpb) * cR + cbase + row % crpb;
        size_t idx = (size_t)crow * N + col;
        float v = acc[i][j][q];
        if (pe) {
          float pos = (float)(row % crpb);
          float ang = pos * expf((float)col * PEK);
          v += (col & 1) ? cosf(ang) : sinf(ang);
        }
        if (mode == MODE_STORE) C[idx] = v;
        else {
          float bb = bias ? bias[col] : 0.f;
          C[idx] = C[idx] + v + bb;
        }
      }
    }
  }
}

// ---------------------------------------------------------------------------
// Output head: out[m,c] = mask[m] ? x[m,c] :
//   x[m,c] + (A@Wv^T) * sigmoid(A@Wg^T + gb[c]).  N=256, BM=64, dual-B.
// ---------------------------------------------------------------------------
__global__ __launch_bounds__(256) void gemm16gate_kernel(
    const _Float16* __restrict__ A, const _Float16* __restrict__ Wv,
    const _Float16* __restrict__ Wg, const float* __restrict__ x,
    const float* __restrict__ gb, const int* __restrict__ mask,
    float* __restrict__ out, int M, int K, int arpb, int aR, int abase) {
  __shared__ _Float16 Al[4][2048];
  __shared__ _Float16 Bva[4][2048];
  __shared__ _Float16 Bga[4][2048];

  const int t = threadIdx.x;
  const int nbm = (M + 63) >> 6;
  const int nwg = gridDim.x;
  int bid = blockIdx.x;
  if ((nwg & 7) == 0) {
    int q = nwg >> 3;
    bid = (bid & 7) * q + (bid >> 3);
  }
  const int bm = bid % nbm, bn = bid / nbm;
  const int lane = t & 63;
  const int w = t >> 6;
  const int wm = w >> 1, wn = w & 1;

  const int r0 = t >> 2;
  const int cp = t & 3;
  const int gc = cp ^ ((r0 >> 1) & 3);
  int gr = bm * 64 + r0;  if (gr >= M) gr = M - 1;
  int ar = (gr / arpb) * aR + abase + gr % arpb;
  const int gcol = bn * 64 + r0;  // N=256 exact
  const _Float16* pA  = A + (size_t)ar * K + gc * 8;
  const _Float16* pBv = Wv + (size_t)gcol * K + gc * 8;
  const _Float16* pBg = Wg + (size_t)gcol * K + gc * 8;

#define STAGE(buf, kt)                                                         \
  do {                                                                         \
    ASYNC16(&Al[buf][t * 8], pA + (size_t)(kt) * 32);                          \
    ASYNC16(&Bva[buf][t * 8], pBv + (size_t)(kt) * 32);                        \
    ASYNC16(&Bga[buf][t * 8], pBg + (size_t)(kt) * 32);                        \
  } while (0)

  f32x4 acv[2][2], acg[2][2];
#pragma unroll
  for (int i = 0; i < 2; i++)
#pragma unroll
    for (int j = 0; j < 2; j++) {
      acv[i][j] = (f32x4){0.f, 0.f, 0.f, 0.f};
      acg[i][j] = (f32x4){0.f, 0.f, 0.f, 0.f};
    }

  const int nt = K >> 5;  // 16
  STAGE(0, 0); STAGE(1, 1); STAGE(2, 2);

  const int rl = lane & 15;
  const int ca = (lane >> 4) ^ ((rl >> 1) & 3);
  for (int kt = 0; kt < nt; ++kt) {
    if (kt < nt - 2)       asm volatile("s_waitcnt vmcnt(6)" ::: "memory");
    else if (kt == nt - 2) asm volatile("s_waitcnt vmcnt(3)" ::: "memory");
    else                   asm volatile("s_waitcnt vmcnt(0)" ::: "memory");
    __builtin_amdgcn_s_barrier();
    const int buf = kt & 3;
    half8 af[2], bv[2], bg2[2];
#pragma unroll
    for (int i = 0; i < 2; i++)
      af[i] = *(const half8*)&Al[buf][(wm * 32 + i * 16 + rl) * 32 + ca * 8];
#pragma unroll
    for (int j = 0; j < 2; j++) {
      bv[j] = *(const half8*)&Bva[buf][(wn * 32 + j * 16 + rl) * 32 + ca * 8];
      bg2[j] = *(const half8*)&Bga[buf][(wn * 32 + j * 16 + rl) * 32 + ca * 8];
    }
#pragma unroll
    for (int i = 0; i < 2; i++)
#pragma unroll
      for (int j = 0; j < 2; j++) {
        acv[i][j] = __builtin_amdgcn_mfma_f32_16x16x32_f16(af[i], bv[j],
                                                           acv[i][j], 0, 0, 0);
        acg[i][j] = __builtin_amdgcn_mfma_f32_16x16x32_f16(af[i], bg2[j],
                                                           acg[i][j], 0, 0, 0);
      }
    if (kt + 3 < nt) STAGE((kt + 3) & 3, kt + 3);
  }
#undef STAGE

  const int rb = bm * 64 + wm * 32 + ((lane >> 4) << 2);
  const int cb = bn * 64 + wn * 32 + (lane & 15);
#pragma unroll
  for (int i = 0; i < 2; i++) {
#pragma unroll
    for (int j = 0; j < 2; j++) {
      int col = cb + j * 16;
#pragma unroll
      for (int q = 0; q < 4; q++) {
        int row = rb + i * 16 + q;
        if (row >= M) continue;
        size_t idx = (size_t)row * DIN_ + col;
        float xv = x[idx];
        float res;
        if (mask[row]) {
          res = xv;
        } else {
          float gate = 1.f / (1.f + expf(-(acg[i][j][q] + gb[col])));
          res = xv + acv[i][j][q] * gate;
        }
        out[idx] = res;
      }
    }
  }
}

// ---------------------------------------------------------------------------
// LayerNorm: one block per row of 512; fp32 math, fp16 output
// ---------------------------------------------------------------------------
__global__ __launch_bounds__(256) void ln_kernel(
    const float* __restrict__ x, const float* __restrict__ g,
    const float* __restrict__ b, _Float16* __restrict__ out) {
  const int row = blockIdx.x;
  const int t = threadIdx.x;
  const float* xr = x + (size_t)row * D_;
  float v0 = xr[t], v1 = xr[t + 256];
  float s = v0 + v1, s2 = v0 * v0 + v1 * v1;
#pragma unroll
  for (int o = 32; o > 0; o >>= 1) {
    s += __shfl_down(s, o);
    s2 += __shfl_down(s2, o);
  }
  __shared__ float w1[4], w2[4], mv[2];
  const int w = t >> 6;
  if ((t & 63) == 0) { w1[w] = s; w2[w] = s2; }
  __syncthreads();
  if (t == 0) {
    float ss = w1[0] + w1[1] + w1[2] + w1[3];
    float ss2 = w2[0] + w2[1] + w2[2] + w2[3];
    float mean = ss * (1.f / D_);
    float var = ss2 * (1.f / D_) - mean * mean;
    mv[0] = mean;
    mv[1] = rsqrtf(var + 1e-5f);
  }
  __syncthreads();
  float mean = mv[0], inv = mv[1];
  _Float16* orow = out + (size_t)row * D_;
  orow[t] = (_Float16)((v0 - mean) * inv * g[t] + b[t]);
  orow[t + 256] = (_Float16)((v1 - mean) * inv * g[t + 256] + b[t + 256]);
}

// ---------------------------------------------------------------------------
// Multi-segment fp32 -> fp16 (13 segments), 16-elem units (64B rd / 32B wr)
// ---------------------------------------------------------------------------
struct ThSegs {
  const float* src[13];
  _Float16* dst[13];
  int cum[14];  // cumulative n16
};
__global__ void tohalf_multi_kernel(ThSegs sg) {
  int total = sg.cum[13];
  for (int i = blockIdx.x * blockDim.x + threadIdx.x; i < total;
       i += gridDim.x * blockDim.x) {
    int s = 0;
    while (i >= sg.cum[s + 1]) s++;
    int off = i - sg.cum[s];
    const float4* p = (const float4*)(sg.src[s] + (size_t)off * 16);
    float4 x = p[0], y = p[1], z = p[2], w = p[3];
    half8 h0 = {(_Float16)x.x, (_Float16)x.y, (_Float16)x.z, (_Float16)x.w,
                (_Float16)y.x, (_Float16)y.y, (_Float16)y.z, (_Float16)y.w};
    half8 h1 = {(_Float16)z.x, (_Float16)z.y, (_Float16)z.z, (_Float16)z.w,
                (_Float16)w.x, (_Float16)w.y, (_Float16)w.z, (_Float16)w.w};
    half8* d = (half8*)(sg.dst[s] + (size_t)off * 16);
    d[0] = h0;
    d[1] = h1;
  }
}

__global__ void tohalf_kernel(const float* __restrict__ src,
                              _Float16* __restrict__ dst, int n8) {
  for (int i = blockIdx.x * blockDim.x + threadIdx.x; i < n8;
       i += gridDim.x * blockDim.x) {
    const float4* s = (const float4*)(src + (size_t)i * 8);
    float4 x = s[0], y = s[1];
    half8 h = {(_Float16)x.x, (_Float16)x.y, (_Float16)x.z, (_Float16)x.w,
               (_Float16)y.x, (_Float16)y.y, (_Float16)y.z, (_Float16)y.w};
    *(half8*)(dst + (size_t)i * 8) = h;
  }
}

// ---------------------------------------------------------------------------
// Transpose out_w (NL,512,48) -> owT (NL,48,512); writes coalesced, once/call
// ---------------------------------------------------------------------------
__global__ void transpose_ow_kernel(const float* __restrict__ out_w,
                                    float* __restrict__ owT) {
  int idx = blockIdx.x * blockDim.x + threadIdx.x;
  const int total = NL_ * 48 * D_;
  if (idx >= total) return;
  int l = idx / (48 * D_);
  int rem = idx % (48 * D_);
  int k = rem / D_;
  int c = rem % D_;
  owT[idx] = out_w[(size_t)l * D_ * 48 + (size_t)c * 48 + k];
}

// ---------------------------------------------------------------------------
// prep: concat rots/trans/mask + padded mask + zero K/V pad columns
// ---------------------------------------------------------------------------
__global__ void prep_kernel(
    const float* __restrict__ vh_rots, const float* __restrict__ vh_trans,
    const float* __restrict__ vl_rots, const float* __restrict__ vl_trans,
    const float* __restrict__ ep_rots, const float* __restrict__ ep_trans,
    const int* __restrict__ vh_mask, const int* __restrict__ vl_mask,
    const int* __restrict__ ep_mask, float* __restrict__ rots,
    float* __restrict__ trans, int* __restrict__ mask,
    int* __restrict__ maskp, float* __restrict__ Kt, float* __restrict__ PKt,
    float* __restrict__ Vt) {
  int idx = blockIdx.x * blockDim.x + threadIdx.x;
  if (idx < B_ * RP_) {
    int b = idx >> 9, r = idx & (RP_ - 1);
    if (r >= R_) {
      maskp[idx] = 1;
      return;
    }
    const float* sr; const float* st; int sm;
    if (r < VH_) {
      sr = vh_rots + (size_t)(b * VH_ + r) * 9;
      st = vh_trans + (size_t)(b * VH_ + r) * 3;
      sm = vh_mask[b * VH_ + r];
    } else if (r < VH_ + VL_) {
      int rr = r - VH_;
      sr = vl_rots + (size_t)(b * VL_ + rr) * 9;
      st = vl_trans + (size_t)(b * VL_ + rr) * 3;
      sm = vl_mask[b * VL_ + rr];
    } else {
      int rr = r - VH_ - VL_;
      sr = ep_rots + (size_t)(b * EP_ + rr) * 9;
      st = ep_trans + (size_t)(b * EP_ + rr) * 3;
      sm = ep_mask[b * EP_ + rr];
    }
    int lin = b * R_ + r;
    maskp[idx] = sm;
    mask[lin] = sm;
#pragma unroll
    for (int k = 0; k < 9; k++) rots[(size_t)lin * 9 + k] = sr[k];
#pragma unroll
    for (int k = 0; k < 3; k++) trans[(size_t)lin * 3 + k] = st[k];
  } else {
    int p = idx - B_ * RP_;
    const int per = B_ * H_ * 3 * (RP_ - R_);
    if (p >= 3 * per) return;
    int a = p / per;
    int q = p % per;
    int chan = q / (RP_ - R_), jj = q % (RP_ - R_);
    float* dst = (a == 0) ? Kt : (a == 1) ? PKt : Vt;
    dst[(size_t)chan * RP_ + R_ + jj] = 0.f;
  }
}

// ---------------------------------------------------------------------------
// Rotate QKV fields; Q-side row-major, K/V-side transposed [b][h][3][j]
// ---------------------------------------------------------------------------
__global__ __launch_bounds__(128) void rotate_kernel(
    const float* __restrict__ qkv_raw, const float* __restrict__ rots,
    const float* __restrict__ trans, float* __restrict__ Qrow,
    float* __restrict__ PQrow, float* __restrict__ Kt,
    float* __restrict__ PKt, float* __restrict__ Vt) {
  const int blk = blockIdx.x;
  const int b = blk / R_;
  const int r = blk % R_;
  const int t = threadIdx.x;
  __shared__ float Rm[9], tr[3], raw[240];
  if (t < 9) Rm[t] = rots[(size_t)blk * 9 + t];
  if (t >= 9 && t < 12) tr[t - 9] = trans[(size_t)blk * 3 + (t - 9)];
  for (int i = t; i < 240; i += 128) raw[i] = qkv_raw[(size_t)blk * 240 + i];
  __syncthreads();
  if (t < 80) {
    int f = t / 16, h = t % 16;
    float x = raw[f * 48 + h * 3 + 0];
    float y = raw[f * 48 + h * 3 + 1];
    float z = raw[f * 48 + h * 3 + 2];
    float r0 = Rm[0] * x + Rm[1] * y + Rm[2] * z;
    float r1 = Rm[3] * x + Rm[4] * y + Rm[5] * z;
    float r2 = Rm[6] * x + Rm[7] * y + Rm[8] * z;
    if (f == 2 || f == 3) { r0 += tr[0]; r1 += tr[1]; r2 += tr[2]; }
    if (f == 0 || f == 2) {
      float* dst = (f == 0) ? Qrow : PQrow;
      size_t o = (size_t)blk * 48 + h * 3;
      dst[o] = r0; dst[o + 1] = r1; dst[o + 2] = r2;
    } else {
      float* dst = (f == 1) ? Kt : (f == 3) ? PKt : Vt;
      size_t base = ((size_t)(b * H_ + h) * 3) * RP_ + r;
      dst[base] = r0; dst[base + RP_] = r1; dst[base + 2 * RP_] = r2;
    }
  }
}

// ---------------------------------------------------------------------------
// Attention: 1024 threads = 16 waves, wave = head (no hh loop). Block per
// (b, i-pair). Fused inverse-rotation + out-projection (transposed owT).
// ---------------------------------------------------------------------------
__global__ __launch_bounds__(1024) void attn2_kernel(
    const float* __restrict__ Qrow, const float* __restrict__ PQrow,
    const float* __restrict__ Kt, const float* __restrict__ PKt,
    const float* __restrict__ Vt, const float* __restrict__ rots,
    const int* __restrict__ mask, const int* __restrict__ maskp,
    const float* __restrict__ rs, const float* __restrict__ ds,
    const float* __restrict__ owT, const float* __restrict__ out_b,
    float* __restrict__ emb) {
  const int blk = blockIdx.x;
  const int b = blk / (R_ / 2);
  const int ip = blk % (R_ / 2);
  const int i0 = ip * 2;
  const int t = threadIdx.x;
  const int lane = t & 63;
  const int h = t >> 6;  // wave = head

  __shared__ float qs[2][48], ps[2][48], og[2][48];
  __shared__ float crs[16], cds[16];
  __shared__ int mi[2];

  if (t < 96) {
    int io = t / 48, k2 = t % 48;
    int i = i0 + io;
    qs[io][k2] = Qrow[((size_t)(b * R_ + i)) * 48 + k2];
    ps[io][k2] = PQrow[((size_t)(b * R_ + i)) * 48 + k2];
  } else if (t < 112) {
    int hh = t - 96;
    const float sc = 0.57735026918962576f;
    crs[hh] = log1pf(expf(rs[hh])) * sc;
    cds[hh] = log1pf(expf(ds[hh])) * sc;
  } else if (t < 114) {
    mi[t - 112] = mask[b * R_ + i0 + (t - 112)];
  }
  __syncthreads();

  float mb[8];
#pragma unroll
  for (int jb = 0; jb < 8; jb++) {
    int j = jb * 64 + lane;
    mb[jb] = maskp[b * RP_ + j] ? -1e9f : 0.f;
  }
  const float bi0 = mi[0] ? -1e9f : 0.f;
  const float bi1 = mi[1] ? -1e9f : 0.f;

  {
    const float sA = crs[h], sD = cds[h];
    const float qx0 = qs[0][h * 3], qy0 = qs[0][h * 3 + 1], qz0 = qs[0][h * 3 + 2];
    const float px0 = ps[0][h * 3], py0 = ps[0][h * 3 + 1], pz0 = ps[0][h * 3 + 2];
    const float qx1 = qs[1][h * 3], qy1 = qs[1][h * 3 + 1], qz1 = qs[1][h * 3 + 2];
    const float px1 = ps[1][h * 3], py1 = ps[1][h * 3 + 1], pz1 = ps[1][h * 3 + 2];
    const float* kb = Kt + ((size_t)(b * H_ + h) * 3) * RP_;
    const float* pb = PKt + ((size_t)(b * H_ + h) * 3) * RP_;
    const float* vb = Vt + ((size_t)(b * H_ + h) * 3) * RP_;

    float l0[8], l1[8];
    float m0 = -3e38f, m1 = -3e38f;
#pragma unroll
    for (int jb = 0; jb < 8; jb++) {
      int j = jb * 64 + lane;
      float kx = kb[j], ky = kb[j + RP_], kz = kb[j + 2 * RP_];
      float pkx = pb[j], pky = pb[j + RP_], pkz = pb[j + 2 * RP_];
      float dx0 = px0 - pkx, dy0 = py0 - pky, dz0 = pz0 - pkz;
      float d0 = sqrtf(dx0 * dx0 + dy0 * dy0 + dz0 * dz0);
      l0[jb] = (qx0 * kx + qy0 * ky + qz0 * kz) * sA - d0 * sD + mb[jb] + bi0;
      m0 = fmaxf(m0, l0[jb]);
      float dx1 = px1 - pkx, dy1 = py1 - pky, dz1 = pz1 - pkz;
      float d1 = sqrtf(dx1 * dx1 + dy1 * dy1 + dz1 * dz1);
      l1[jb] = (qx1 * kx + qy1 * ky + qz1 * kz) * sA - d1 * sD + mb[jb] + bi1;
      m1 = fmaxf(m1, l1[jb]);
    }
#pragma unroll
    for (int s = 1; s < 64; s <<= 1) {
      m0 = fmaxf(m0, __shfl_xor(m0, s));
      m1 = fmaxf(m1, __shfl_xor(m1, s));
    }
    float s0 = 0.f, s1 = 0.f;
    float ox0 = 0.f, oy0 = 0.f, oz0 = 0.f, ox1 = 0.f, oy1 = 0.f, oz1 = 0.f;
#pragma unroll
    for (int jb = 0; jb < 8; jb++) {
      int j = jb * 64 + lane;
      float p0 = expf(l0[jb] - m0);
      float p1 = expf(l1[jb] - m1);
      s0 += p0; s1 += p1;
      float vx = vb[j], vy = vb[j + RP_], vz = vb[j + 2 * RP_];
      ox0 += p0 * vx; oy0 += p0 * vy; oz0 += p0 * vz;
      ox1 += p1 * vx; oy1 += p1 * vy; oz1 += p1 * vz;
    }
#pragma unroll
    for (int s = 1; s < 64; s <<= 1) {
      s0 += __shfl_xor(s0, s); s1 += __shfl_xor(s1, s);
      ox0 += __shfl_xor(ox0, s); oy0 += __shfl_xor(oy0, s); oz0 += __shfl_xor(oz0, s);
      ox1 += __shfl_xor(ox1, s); oy1 += __shfl_xor(oy1, s); oz1 += __shfl_xor(oz1, s);
    }
    if (lane == 0) {
      og[0][h * 3] = ox0 / s0; og[0][h * 3 + 1] = oy0 / s0; og[0][h * 3 + 2] = oz0 / s0;
      og[1][h * 3] = ox1 / s1; og[1][h * 3 + 1] = oy1 / s1; og[1][h * 3 + 2] = oz1 / s1;
    }
  }
  __syncthreads();
  // inverse rotation in-place on og
  float r0v0 = 0.f, r0v1 = 0.f;
  if (t < 48) {
    int hh = t / 3, i3 = t % 3;
    const float* Rm0 = rots + ((size_t)(b * R_ + i0)) * 9;
    const float* Rm1 = rots + ((size_t)(b * R_ + i0 + 1)) * 9;
    r0v0 = Rm0[0 + i3] * og[0][hh * 3 + 0] + Rm0[3 + i3] * og[0][hh * 3 + 1] +
           Rm0[6 + i3] * og[0][hh * 3 + 2];
    r0v1 = Rm1[0 + i3] * og[1][hh * 3 + 0] + Rm1[3 + i3] * og[1][hh * 3 + 1] +
           Rm1[6 + i3] * og[1][hh * 3 + 2];
  }
  __syncthreads();
  if (t < 48) { og[0][t] = r0v0; og[1][t] = r0v1; }
  __syncthreads();
  // fused out-projection, single pass: io = t>>9, c = t&511
  {
    const int io = t >> 9;
    const int c = t & 511;
    float* erow = emb + ((size_t)(b * R_ + i0 + io)) * D_;
    float a0 = 0.f, a1 = 0.f, a2 = 0.f, a3 = 0.f;
#pragma unroll
    for (int k = 0; k < 48; k += 4) {
      a0 += og[io][k + 0] * owT[(size_t)(k + 0) * D_ + c];
      a1 += og[io][k + 1] * owT[(size_t)(k + 1) * D_ + c];
      a2 += og[io][k + 2] * owT[(size_t)(k + 2) * D_ + c];
      a3 += og[io][k + 3] * owT[(size_t)(k + 3) * D_ + c];
    }
    erow[c] += out_b[c] + ((a0 + a1) + (a2 + a3));
  }
}

// ---------------------------------------------------------------------------
extern "C" void kernel_launch(void* const* d_in, const int* in_sizes, int n_in,
                              void* d_out, int out_size, void* d_ws, size_t ws_size,
                              hipStream_t stream) {
  const float* vh_x = (const float*)d_in[0];
  const float* vl_x = (const float*)d_in[1];
  const float* vh_rots = (const float*)d_in[2];
  const float* vh_trans = (const float*)d_in[3];
  const float* vl_rots = (const float*)d_in[4];
  const float* vl_trans = (const float*)d_in[5];
  const float* ep_feats = (const float*)d_in[6];
  const float* ep_rots = (const float*)d_in[7];
  const float* ep_trans = (const float*)d_in[8];
  const int* vh_mask = (const int*)d_in[9];
  const int* vl_mask = (const int*)d_in[10];
  const int* ep_mask = (const int*)d_in[11];
  const float* vh_emb_w = (const float*)d_in[12];
  const float* vl_emb_w = (const float*)d_in[13];
  const float* tgt_emb_w = (const float*)d_in[14];
  const float* qkv_w = (const float*)d_in[15];
  const float* out_w = (const float*)d_in[16];
  const float* out_b = (const float*)d_in[17];
  const float* ln_g = (const float*)d_in[18];
  const float* ln_b = (const float*)d_in[19];
  const float* r_scale = (const float*)d_in[20];
  const float* d_scale = (const float*)d_in[21];
  const float* ln2_g = (const float*)d_in[22];
  const float* ln2_b = (const float*)d_in[23];
  const float* w12 = (const float*)d_in[24];
  const float* w3 = (const float*)d_in[25];
  const float* out_vh_w = (const float*)d_in[26];
  const float* out_vh_gate_w = (const float*)d_in[27];
  const float* out_vh_gate_b = (const float*)d_in[28];
  const float* out_vl_w = (const float*)d_in[29];
  const float* out_vl_gate_w = (const float*)d_in[30];
  const float* out_vl_gate_b = (const float*)d_in[31];

  const int BR = B_ * R_;  // 2024

  // ---- workspace layout (256B-aligned) ----
  uint8_t* P = (uint8_t*)d_ws;
  auto alloc = [&](size_t bytes) {
    uint8_t* p = P;
    P += (bytes + 255) & ~(size_t)255;
    return p;
  };
  float* emb = (float*)alloc((size_t)BR * D_ * 4);
  _Float16* xnh = (_Float16*)alloc((size_t)BR * D_ * 2);
  float* qkvr = (float*)alloc((size_t)BR * 240 * 4);
  float* Qrow = (float*)alloc((size_t)BR * 48 * 4);
  float* PQrow = (float*)alloc((size_t)BR * 48 * 4);
  float* Kt = (float*)alloc((size_t)B_ * H_ * 3 * RP_ * 4);
  float* PKt = (float*)alloc((size_t)B_ * H_ * 3 * RP_ * 4);
  float* Vt = (float*)alloc((size_t)B_ * H_ * 3 * RP_ * 4);
  _Float16* ghalf = (_Float16*)alloc((size_t)BR * HID_ * 2);
  float* rots_c = (float*)alloc((size_t)BR * 9 * 4);
  float* trans_c = (float*)alloc((size_t)BR * 3 * 4);
  int* mask_c = (int*)alloc((size_t)BR * 4);
  int* maskp = (int*)alloc((size_t)B_ * RP_ * 4);
  float* owT = (float*)alloc((size_t)NL_ * 48 * D_ * 4);
  _Float16* embh = (_Float16*)alloc((size_t)BR * D_ * 2);
  _Float16* qkvh = (_Float16*)alloc((size_t)NL_ * 240 * D_ * 2);
  _Float16* w12h = (_Float16*)alloc((size_t)NL_ * 2 * HID_ * D_ * 2);
  _Float16* w3h = (_Float16*)alloc((size_t)NL_ * D_ * HID_ * 2);
  _Float16* vhxh = (_Float16*)alloc((size_t)B_ * VH_ * DIN_ * 2);
  _Float16* vlxh = (_Float16*)alloc((size_t)B_ * VL_ * DIN_ * 2);
  _Float16* eph = (_Float16*)alloc((size_t)B_ * EP_ * DEP_ * 2);
  _Float16* vhewh = (_Float16*)alloc((size_t)D_ * DIN_ * 2);
  _Float16* vlewh = (_Float16*)alloc((size_t)D_ * DIN_ * 2);
  _Float16* tgewh = (_Float16*)alloc((size_t)D_ * DEP_ * 2);
  _Float16* ovhw = (_Float16*)alloc((size_t)DIN_ * D_ * 2);
  _Float16* ovhgw = (_Float16*)alloc((size_t)DIN_ * D_ * 2);
  _Float16* ovlw = (_Float16*)alloc((size_t)DIN_ * D_ * 2);
  _Float16* ovlgw = (_Float16*)alloc((size_t)DIN_ * D_ * 2);

  // one multi-segment fp32->fp16 conversion (weights + inputs), 16-elem units
  {
    ThSegs sg;
    const float* srcs[13] = {qkv_w, w12, w3, vh_x, vl_x, ep_feats,
                             vh_emb_w, vl_emb_w, tgt_emb_w,
                             out_vh_w, out_vh_gate_w, out_vl_w, out_vl_gate_w};
    _Float16* dsts[13] = {qkvh, w12h, w3h, vhxh, vlxh, eph,
                          vhewh, vlewh, tgewh, ovhw, ovhgw, ovlw, ovlgw};
    int n16s[13] = {NL_ * 240 * D_ / 16, NL_ * 2 * HID_ * D_ / 16,
                    NL_ * D_ * HID_ / 16, B_ * VH_ * DIN_ / 16,
                    B_ * VL_ * DIN_ / 16, B_ * EP_ * DEP_ / 16,
                    D_ * DIN_ / 16, D_ * DIN_ / 16, D_ * DEP_ / 16,
                    DIN_ * D_ / 16, DIN_ * D_ / 16, DIN_ * D_ / 16,
                    DIN_ * D_ / 16};
    int c = 0;
    for (int i = 0; i < 13; i++) {
      sg.src[i] = srcs[i]; sg.dst[i] = dsts[i];
      sg.cum[i] = c; c += n16s[i];
    }
    sg.cum[13] = c;
    tohalf_multi_kernel<<<2048, 256, 0, stream>>>(sg);
  }

  // transpose out_w for the attn epilogue (once per call)
  {
    int total = NL_ * 48 * D_;
    transpose_ow_kernel<<<(total + 255) / 256, 256, 0, stream>>>(out_w, owT);
  }

  // prep: concat + padded mask + K/V pad zero
  {
    int total = B_ * RP_ + 3 * B_ * H_ * 3 * (RP_ - R_);
    prep_kernel<<<(total + 255) / 256, 256, 0, stream>>>(
        vh_rots, vh_trans, vl_rots, vl_trans, ep_rots, ep_trans, vh_mask,
        vl_mask, ep_mask, rots_c, trans_c, mask_c, maskp, Kt, PKt, Vt);
  }

  auto gemm16b = [&](const _Float16* A, const _Float16* W, float* C,
                     const float* bias, int M, int N, int K, int mode,
                     int crpb, int cR, int cbase, int pe) {
    int nbm = (M + 63) / 64, nbn = (N + 63) / 64;
    gemm16b_kernel<<<nbm * nbn, 256, 0, stream>>>(A, W, C, bias, M, N, K, mode,
                                                  crpb, cR, cbase, pe);
  };

  // embeddings (fp16 MFMA, fused PE, remapped into emb)
  gemm16b(vhxh, vhewh, emb, nullptr, B_ * VH_, D_, DIN_, MODE_STORE,
          VH_, R_, 0, 1);
  gemm16b(vlxh, vlewh, emb, nullptr, B_ * VL_, D_, DIN_, MODE_STORE,
          VL_, R_, VH_, 1);
  gemm16b(eph, tgewh, emb, nullptr, B_ * EP_, D_, DEP_, MODE_STORE,
          EP_, R_, VH_ + VL_, 0);

  for (int l = 0; l < NL_; l++) {
    const _Float16* qwh = qkvh + (size_t)l * 240 * D_;
    const float* owTl = owT + (size_t)l * 48 * D_;
    const float* obias = out_b + (size_t)l * D_;
    const float* lg = ln_g + (size_t)l * D_;
    const float* lb = ln_b + (size_t)l * D_;
    const float* l2g = ln2_g + (size_t)l * D_;
    const float* l2b = ln2_b + (size_t)l * D_;
    const float* rs = r_scale + (size_t)l * H_;
    const float* dsc = d_scale + (size_t)l * H_;
    const _Float16* w12ah = w12h + (size_t)l * 2 * HID_ * D_;
    const _Float16* w12bh = w12ah + (size_t)HID_ * D_;
    const _Float16* w3lh = w3h + (size_t)l * D_ * HID_;

    // attention (out-projection fused into attn2, transposed weights)
    ln_kernel<<<BR, 256, 0, stream>>>(emb, lg, lb, xnh);
    gemm16b(xnh, qwh, qkvr, nullptr, BR, 240, D_, MODE_STORE, BR, BR, 0, 0);
    rotate_kernel<<<BR, 128, 0, stream>>>(qkvr, rots_c, trans_c, Qrow, PQrow,
                                          Kt, PKt, Vt);
    attn2_kernel<<<B_ * (R_ / 2), 1024, 0, stream>>>(
        Qrow, PQrow, Kt, PKt, Vt, rots_c, mask_c, maskp, rs, dsc, owTl, obias,
        emb);

    // swiglu
    ln_kernel<<<BR, 256, 0, stream>>>(emb, l2g, l2b, xnh);
    {
      int nbm = (BR + 127) / 128, nbn = HID_ / 64;
      gemm16sw_kernel<<<nbm * nbn, 256, 0, stream>>>(xnh, w12ah, w12bh, ghalf,
                                                     BR, D_);
    }
    gemm16b(ghalf, w3lh, emb, nullptr, BR, D_, HID_, MODE_ADD_BIAS,
            BR, BR, 0, 0);
  }

  // output heads: emb -> fp16, then fused dual-GEMM + gate -> d_out
  tohalf_kernel<<<1024, 256, 0, stream>>>(emb, embh, BR * D_ / 8);
  {
    int M = B_ * VH_;
    int nbm = (M + 63) / 64;
    gemm16gate_kernel<<<nbm * 4, 256, 0, stream>>>(
        embh, ovhw, ovhgw, vh_x, out_vh_gate_b, vh_mask, (float*)d_out, M, D_,
        VH_, R_, 0);
  }
  {
    int M = B_ * VL_;
    int nbm = (M + 63) / 64;
    gemm16gate_kernel<<<nbm * 4, 256, 0, stream>>>(
        embh, ovlw, ovlgw, vl_x, out_vl_gate_b, vl_mask,
        (float*)d_out + (size_t)B_ * VH_ * DIN_, M, D_, VL_, R_, VH_);
  }
}

// Round 10
// 1082.516 us; speedup vs baseline: 1.1081x; 1.1081x over previous
//
#include <hip/hip_runtime.h>
#include <hip/hip_bf16.h>
#include <math.h>
#include <stdint.h>

// Problem constants
#define B_ 4
#define VH_ 130
#define VL_ 120
#define EP_ 256
#define R_ 506           // VH+VL+EP
#define RP_ 512          // padded R for K/V layouts
#define DIN_ 256
#define DEP_ 128
#define D_ 512
#define H_ 16
#define NL_ 8
#define HID_ 2048

#define MODE_STORE 0
#define MODE_ADD_BIAS 1

typedef _Float16 half8 __attribute__((ext_vector_type(8)));
typedef float f32x4 __attribute__((ext_vector_type(4)));

// async global->LDS 16B copy (width literal)
#define ASYNC16(ldsdst, gsrc)                                                  \
  __builtin_amdgcn_global_load_lds(                                            \
      (const __attribute__((address_space(1))) unsigned int*)(gsrc),           \
      (__attribute__((address_space(3))) unsigned int*)(ldsdst), 16, 0, 0)

// ---------------------------------------------------------------------------
// fp16 MFMA GEMM, BM=128 BN=64, 4-deep pipeline, fused SwiGLU (dual-B).
// ---------------------------------------------------------------------------
__global__ __launch_bounds__(256) void gemm16sw_kernel(
    const _Float16* __restrict__ A, const _Float16* __restrict__ Wa,
    const _Float16* __restrict__ Wv, _Float16* __restrict__ Gh,
    int M, int K) {
  __shared__ _Float16 Al[4][4096];
  __shared__ _Float16 Ba[4][2048];
  __shared__ _Float16 Bv[4][2048];

  const int t = threadIdx.x;
  const int nbm = (M + 127) >> 7;
  const int nwg = gridDim.x;
  int bid = blockIdx.x;
  if ((nwg & 7) == 0) {
    int q = nwg >> 3;
    bid = (bid & 7) * q + (bid >> 3);
  }
  const int bm = bid % nbm, bn = bid / nbm;
  const int lane = t & 63;
  const int w = t >> 6;
  const int wm = w >> 1, wn = w & 1;

  const int r0 = t >> 2;
  const int cp = t & 3;
  const int gc = cp ^ ((r0 >> 1) & 3);
  int gr0 = bm * 128 + r0;       if (gr0 >= M) gr0 = M - 1;
  int gr1 = bm * 128 + 64 + r0;  if (gr1 >= M) gr1 = M - 1;
  const int gcol = bn * 64 + r0;  // N=2048 exact
  const _Float16* pA0 = A + (size_t)gr0 * K + gc * 8;
  const _Float16* pA1 = A + (size_t)gr1 * K + gc * 8;
  const _Float16* pBa = Wa + (size_t)gcol * K + gc * 8;
  const _Float16* pBv = Wv + (size_t)gcol * K + gc * 8;

#define STAGE(buf, kt)                                                         \
  do {                                                                         \
    ASYNC16(&Al[buf][t * 8], pA0 + (size_t)(kt) * 32);                         \
    ASYNC16(&Al[buf][2048 + t * 8], pA1 + (size_t)(kt) * 32);                  \
    ASYNC16(&Ba[buf][t * 8], pBa + (size_t)(kt) * 32);                         \
    ASYNC16(&Bv[buf][t * 8], pBv + (size_t)(kt) * 32);                         \
  } while (0)

  f32x4 aca[4][2], acv[4][2];
#pragma unroll
  for (int i = 0; i < 4; i++)
#pragma unroll
    for (int j = 0; j < 2; j++) {
      aca[i][j] = (f32x4){0.f, 0.f, 0.f, 0.f};
      acv[i][j] = (f32x4){0.f, 0.f, 0.f, 0.f};
    }

  const int nt = K >> 5;
  STAGE(0, 0); STAGE(1, 1); STAGE(2, 2);

  const int rl = lane & 15;
  const int ca = (lane >> 4) ^ ((rl >> 1) & 3);
  for (int kt = 0; kt < nt; ++kt) {
    if (kt < nt - 2)       asm volatile("s_waitcnt vmcnt(8)" ::: "memory");
    else if (kt == nt - 2) asm volatile("s_waitcnt vmcnt(4)" ::: "memory");
    else                   asm volatile("s_waitcnt vmcnt(0)" ::: "memory");
    __builtin_amdgcn_s_barrier();
    const int buf = kt & 3;
    const _Float16* Ab  = &Al[buf][(wm * 64 + rl) * 32 + ca * 8];
    const _Float16* Bab = &Ba[buf][(wn * 32 + rl) * 32 + ca * 8];
    const _Float16* Bvb = &Bv[buf][(wn * 32 + rl) * 32 + ca * 8];
    half8 af[4], bfa[2], bfv[2];
#pragma unroll
    for (int i = 0; i < 4; i++) af[i] = *(const half8*)(Ab + i * 512);
#pragma unroll
    for (int j = 0; j < 2; j++) {
      bfa[j] = *(const half8*)(Bab + j * 512);
      bfv[j] = *(const half8*)(Bvb + j * 512);
    }
#pragma unroll
    for (int i = 0; i < 4; i++)
#pragma unroll
      for (int j = 0; j < 2; j++) {
        aca[i][j] = __builtin_amdgcn_mfma_f32_16x16x32_f16(af[i], bfa[j],
                                                           aca[i][j], 0, 0, 0);
        acv[i][j] = __builtin_amdgcn_mfma_f32_16x16x32_f16(af[i], bfv[j],
                                                           acv[i][j], 0, 0, 0);
      }
    if (kt + 3 < nt) STAGE((kt + 3) & 3, kt + 3);
  }
#undef STAGE

  const int rb = bm * 128 + wm * 64 + ((lane >> 4) << 2);
  const int cb = bn * 64 + wn * 32 + (lane & 15);
#pragma unroll
  for (int i = 0; i < 4; i++) {
#pragma unroll
    for (int j = 0; j < 2; j++) {
      int col = cb + j * 16;
#pragma unroll
      for (int q = 0; q < 4; q++) {
        int row = rb + i * 16 + q;
        if (row >= M) continue;
        float a = aca[i][j][q];
        float v = acv[i][j][q];
        Gh[(size_t)row * HID_ + col] = (_Float16)((a / (1.f + expf(-a))) * v);
      }
    }
  }
}

// ---------------------------------------------------------------------------
// fp16 MFMA GEMM, BM=64 BN=64, 4-deep pipeline, C-row-remap + optional PE.
// ---------------------------------------------------------------------------
__global__ __launch_bounds__(256) void gemm16b_kernel(
    const _Float16* __restrict__ A, const _Float16* __restrict__ W,
    float* __restrict__ C, const float* __restrict__ bias,
    int M, int N, int K, int mode, int crpb, int cR, int cbase, int pe) {
  __shared__ _Float16 Al[4][2048];
  __shared__ _Float16 Bl[4][2048];

  const int t = threadIdx.x;
  const int nbm = (M + 63) >> 6;
  const int nwg = gridDim.x;
  int bid = blockIdx.x;
  if ((nwg & 7) == 0) {
    int q = nwg >> 3;
    bid = (bid & 7) * q + (bid >> 3);
  }
  const int bm = bid % nbm, bn = bid / nbm;
  const int lane = t & 63;
  const int w = t >> 6;
  const int wm = w >> 1, wn = w & 1;

  const int r0 = t >> 2;
  const int cp = t & 3;
  const int gc = cp ^ ((r0 >> 1) & 3);
  int gr = bm * 64 + r0;    if (gr >= M) gr = M - 1;
  int gcol = bn * 64 + r0;  if (gcol >= N) gcol = N - 1;
  const _Float16* pA = A + (size_t)gr * K + gc * 8;
  const _Float16* pB = W + (size_t)gcol * K + gc * 8;

#define STAGE(buf, kt)                                                         \
  do {                                                                         \
    ASYNC16(&Al[buf][t * 8], pA + (size_t)(kt) * 32);                          \
    ASYNC16(&Bl[buf][t * 8], pB + (size_t)(kt) * 32);                          \
  } while (0)

  f32x4 acc[2][2];
#pragma unroll
  for (int i = 0; i < 2; i++)
#pragma unroll
    for (int j = 0; j < 2; j++) acc[i][j] = (f32x4){0.f, 0.f, 0.f, 0.f};

  const int nt = K >> 5;  // >= 4 at all call sites
  STAGE(0, 0); STAGE(1, 1); STAGE(2, 2);

  const int rl = lane & 15;
  const int ca = (lane >> 4) ^ ((rl >> 1) & 3);
  for (int kt = 0; kt < nt; ++kt) {
    if (kt < nt - 2)       asm volatile("s_waitcnt vmcnt(4)" ::: "memory");
    else if (kt == nt - 2) asm volatile("s_waitcnt vmcnt(2)" ::: "memory");
    else                   asm volatile("s_waitcnt vmcnt(0)" ::: "memory");
    __builtin_amdgcn_s_barrier();
    const int buf = kt & 3;
    half8 af[2], bf[2];
#pragma unroll
    for (int i = 0; i < 2; i++)
      af[i] = *(const half8*)&Al[buf][(wm * 32 + i * 16 + rl) * 32 + ca * 8];
#pragma unroll
    for (int j = 0; j < 2; j++)
      bf[j] = *(const half8*)&Bl[buf][(wn * 32 + j * 16 + rl) * 32 + ca * 8];
#pragma unroll
    for (int i = 0; i < 2; i++)
#pragma unroll
      for (int j = 0; j < 2; j++)
        acc[i][j] = __builtin_amdgcn_mfma_f32_16x16x32_f16(af[i], bf[j],
                                                           acc[i][j], 0, 0, 0);
    if (kt + 3 < nt) STAGE((kt + 3) & 3, kt + 3);
  }
#undef STAGE

  const float PEK = -0.02703623196464017f;  // -2*ln(1000)/511
  const int rb = bm * 64 + wm * 32 + ((lane >> 4) << 2);
  const int cb = bn * 64 + wn * 32 + (lane & 15);
#pragma unroll
  for (int i = 0; i < 2; i++) {
#pragma unroll
    for (int j = 0; j < 2; j++) {
      int col = cb + j * 16;
      if (col >= N) continue;
#pragma unroll
      for (int q = 0; q < 4; q++) {
        int row = rb + i * 16 + q;
        if (row >= M) continue;
        int crow = (row / crpb) * cR + cbase + row % crpb;
        size_t idx = (size_t)crow * N + col;
        float v = acc[i][j][q];
        if (pe) {
          float pos = (float)(row % crpb);
          float ang = pos * expf((float)col * PEK);
          v += (col & 1) ? cosf(ang) : sinf(ang);
        }
        if (mode == MODE_STORE) C[idx] = v;
        else {
          float bb = bias ? bias[col] : 0.f;
          C[idx] = C[idx] + v + bb;
        }
      }
    }
  }
}

// ---------------------------------------------------------------------------
// Output head: out[m,c] = mask[m] ? x[m,c] :
//   x[m,c] + (A@Wv^T) * sigmoid(A@Wg^T + gb[c]).  N=256, BM=64, dual-B.
// ---------------------------------------------------------------------------
__global__ __launch_bounds__(256) void gemm16gate_kernel(
    const _Float16* __restrict__ A, const _Float16* __restrict__ Wv,
    const _Float16* __restrict__ Wg, const float* __restrict__ x,
    const float* __restrict__ gb, const int* __restrict__ mask,
    float* __restrict__ out, int M, int K, int arpb, int aR, int abase) {
  __shared__ _Float16 Al[4][2048];
  __shared__ _Float16 Bva[4][2048];
  __shared__ _Float16 Bga[4][2048];

  const int t = threadIdx.x;
  const int nbm = (M + 63) >> 6;
  const int nwg = gridDim.x;
  int bid = blockIdx.x;
  if ((nwg & 7) == 0) {
    int q = nwg >> 3;
    bid = (bid & 7) * q + (bid >> 3);
  }
  const int bm = bid % nbm, bn = bid / nbm;
  const int lane = t & 63;
  const int w = t >> 6;
  const int wm = w >> 1, wn = w & 1;

  const int r0 = t >> 2;
  const int cp = t & 3;
  const int gc = cp ^ ((r0 >> 1) & 3);
  int gr = bm * 64 + r0;  if (gr >= M) gr = M - 1;
  int ar = (gr / arpb) * aR + abase + gr % arpb;
  const int gcol = bn * 64 + r0;  // N=256 exact
  const _Float16* pA  = A + (size_t)ar * K + gc * 8;
  const _Float16* pBv = Wv + (size_t)gcol * K + gc * 8;
  const _Float16* pBg = Wg + (size_t)gcol * K + gc * 8;

#define STAGE(buf, kt)                                                         \
  do {                                                                         \
    ASYNC16(&Al[buf][t * 8], pA + (size_t)(kt) * 32);                          \
    ASYNC16(&Bva[buf][t * 8], pBv + (size_t)(kt) * 32);                        \
    ASYNC16(&Bga[buf][t * 8], pBg + (size_t)(kt) * 32);                        \
  } while (0)

  f32x4 acv[2][2], acg[2][2];
#pragma unroll
  for (int i = 0; i < 2; i++)
#pragma unroll
    for (int j = 0; j < 2; j++) {
      acv[i][j] = (f32x4){0.f, 0.f, 0.f, 0.f};
      acg[i][j] = (f32x4){0.f, 0.f, 0.f, 0.f};
    }

  const int nt = K >> 5;  // 16
  STAGE(0, 0); STAGE(1, 1); STAGE(2, 2);

  const int rl = lane & 15;
  const int ca = (lane >> 4) ^ ((rl >> 1) & 3);
  for (int kt = 0; kt < nt; ++kt) {
    if (kt < nt - 2)       asm volatile("s_waitcnt vmcnt(6)" ::: "memory");
    else if (kt == nt - 2) asm volatile("s_waitcnt vmcnt(3)" ::: "memory");
    else                   asm volatile("s_waitcnt vmcnt(0)" ::: "memory");
    __builtin_amdgcn_s_barrier();
    const int buf = kt & 3;
    half8 af[2], bv[2], bg2[2];
#pragma unroll
    for (int i = 0; i < 2; i++)
      af[i] = *(const half8*)&Al[buf][(wm * 32 + i * 16 + rl) * 32 + ca * 8];
#pragma unroll
    for (int j = 0; j < 2; j++) {
      bv[j] = *(const half8*)&Bva[buf][(wn * 32 + j * 16 + rl) * 32 + ca * 8];
      bg2[j] = *(const half8*)&Bga[buf][(wn * 32 + j * 16 + rl) * 32 + ca * 8];
    }
#pragma unroll
    for (int i = 0; i < 2; i++)
#pragma unroll
      for (int j = 0; j < 2; j++) {
        acv[i][j] = __builtin_amdgcn_mfma_f32_16x16x32_f16(af[i], bv[j],
                                                           acv[i][j], 0, 0, 0);
        acg[i][j] = __builtin_amdgcn_mfma_f32_16x16x32_f16(af[i], bg2[j],
                                                           acg[i][j], 0, 0, 0);
      }
    if (kt + 3 < nt) STAGE((kt + 3) & 3, kt + 3);
  }
#undef STAGE

  const int rb = bm * 64 + wm * 32 + ((lane >> 4) << 2);
  const int cb = bn * 64 + wn * 32 + (lane & 15);
#pragma unroll
  for (int i = 0; i < 2; i++) {
#pragma unroll
    for (int j = 0; j < 2; j++) {
      int col = cb + j * 16;
#pragma unroll
      for (int q = 0; q < 4; q++) {
        int row = rb + i * 16 + q;
        if (row >= M) continue;
        size_t idx = (size_t)row * DIN_ + col;
        float xv = x[idx];
        float res;
        if (mask[row]) {
          res = xv;
        } else {
          float gate = 1.f / (1.f + expf(-(acg[i][j][q] + gb[col])));
          res = xv + acv[i][j][q] * gate;
        }
        out[idx] = res;
      }
    }
  }
}

// ---------------------------------------------------------------------------
// LayerNorm: one block per row of 512; fp32 math, fp16 output
// ---------------------------------------------------------------------------
__global__ __launch_bounds__(256) void ln_kernel(
    const float* __restrict__ x, const float* __restrict__ g,
    const float* __restrict__ b, _Float16* __restrict__ out) {
  const int row = blockIdx.x;
  const int t = threadIdx.x;
  const float* xr = x + (size_t)row * D_;
  float v0 = xr[t], v1 = xr[t + 256];
  float s = v0 + v1, s2 = v0 * v0 + v1 * v1;
#pragma unroll
  for (int o = 32; o > 0; o >>= 1) {
    s += __shfl_down(s, o);
    s2 += __shfl_down(s2, o);
  }
  __shared__ float w1[4], w2[4], mv[2];
  const int w = t >> 6;
  if ((t & 63) == 0) { w1[w] = s; w2[w] = s2; }
  __syncthreads();
  if (t == 0) {
    float ss = w1[0] + w1[1] + w1[2] + w1[3];
    float ss2 = w2[0] + w2[1] + w2[2] + w2[3];
    float mean = ss * (1.f / D_);
    float var = ss2 * (1.f / D_) - mean * mean;
    mv[0] = mean;
    mv[1] = rsqrtf(var + 1e-5f);
  }
  __syncthreads();
  float mean = mv[0], inv = mv[1];
  _Float16* orow = out + (size_t)row * D_;
  orow[t] = (_Float16)((v0 - mean) * inv * g[t] + b[t]);
  orow[t + 256] = (_Float16)((v1 - mean) * inv * g[t + 256] + b[t + 256]);
}

// ---------------------------------------------------------------------------
// Multi-segment fp32 -> fp16 (13 segments), 16-elem units (64B rd / 32B wr)
// ---------------------------------------------------------------------------
struct ThSegs {
  const float* src[13];
  _Float16* dst[13];
  int cum[14];  // cumulative n16
};
__global__ void tohalf_multi_kernel(ThSegs sg) {
  int total = sg.cum[13];
  for (int i = blockIdx.x * blockDim.x + threadIdx.x; i < total;
       i += gridDim.x * blockDim.x) {
    int s = 0;
    while (i >= sg.cum[s + 1]) s++;
    int off = i - sg.cum[s];
    const float4* p = (const float4*)(sg.src[s] + (size_t)off * 16);
    float4 x = p[0], y = p[1], z = p[2], w = p[3];
    half8 h0 = {(_Float16)x.x, (_Float16)x.y, (_Float16)x.z, (_Float16)x.w,
                (_Float16)y.x, (_Float16)y.y, (_Float16)y.z, (_Float16)y.w};
    half8 h1 = {(_Float16)z.x, (_Float16)z.y, (_Float16)z.z, (_Float16)z.w,
                (_Float16)w.x, (_Float16)w.y, (_Float16)w.z, (_Float16)w.w};
    half8* d = (half8*)(sg.dst[s] + (size_t)off * 16);
    d[0] = h0;
    d[1] = h1;
  }
}

__global__ void tohalf_kernel(const float* __restrict__ src,
                              _Float16* __restrict__ dst, int n8) {
  for (int i = blockIdx.x * blockDim.x + threadIdx.x; i < n8;
       i += gridDim.x * blockDim.x) {
    const float4* s = (const float4*)(src + (size_t)i * 8);
    float4 x = s[0], y = s[1];
    half8 h = {(_Float16)x.x, (_Float16)x.y, (_Float16)x.z, (_Float16)x.w,
               (_Float16)y.x, (_Float16)y.y, (_Float16)y.z, (_Float16)y.w};
    *(half8*)(dst + (size_t)i * 8) = h;
  }
}

// ---------------------------------------------------------------------------
// Transpose out_w (NL,512,48) -> owT (NL,48,512)
// ---------------------------------------------------------------------------
__global__ void transpose_ow_kernel(const float* __restrict__ out_w,
                                    float* __restrict__ owT) {
  int idx = blockIdx.x * blockDim.x + threadIdx.x;
  const int total = NL_ * 48 * D_;
  if (idx >= total) return;
  int l = idx / (48 * D_);
  int rem = idx % (48 * D_);
  int k = rem / D_;
  int c = rem % D_;
  owT[idx] = out_w[(size_t)l * D_ * 48 + (size_t)c * 48 + k];
}

// ---------------------------------------------------------------------------
// prep: concat rots/trans/mask + padded mask + zero K/V pad rows (xyz0 layout)
// K/Pk/V layout: [b][h][j][4] floats (xyz + 0 pad)
// ---------------------------------------------------------------------------
__global__ void prep_kernel(
    const float* __restrict__ vh_rots, const float* __restrict__ vh_trans,
    const float* __restrict__ vl_rots, const float* __restrict__ vl_trans,
    const float* __restrict__ ep_rots, const float* __restrict__ ep_trans,
    const int* __restrict__ vh_mask, const int* __restrict__ vl_mask,
    const int* __restrict__ ep_mask, float* __restrict__ rots,
    float* __restrict__ trans, int* __restrict__ mask,
    int* __restrict__ maskp, float* __restrict__ Kt, float* __restrict__ PKt,
    float* __restrict__ Vt) {
  int idx = blockIdx.x * blockDim.x + threadIdx.x;
  if (idx < B_ * RP_) {
    int b = idx >> 9, r = idx & (RP_ - 1);
    if (r >= R_) {
      maskp[idx] = 1;
      return;
    }
    const float* sr; const float* st; int sm;
    if (r < VH_) {
      sr = vh_rots + (size_t)(b * VH_ + r) * 9;
      st = vh_trans + (size_t)(b * VH_ + r) * 3;
      sm = vh_mask[b * VH_ + r];
    } else if (r < VH_ + VL_) {
      int rr = r - VH_;
      sr = vl_rots + (size_t)(b * VL_ + rr) * 9;
      st = vl_trans + (size_t)(b * VL_ + rr) * 3;
      sm = vl_mask[b * VL_ + rr];
    } else {
      int rr = r - VH_ - VL_;
      sr = ep_rots + (size_t)(b * EP_ + rr) * 9;
      st = ep_trans + (size_t)(b * EP_ + rr) * 3;
      sm = ep_mask[b * EP_ + rr];
    }
    int lin = b * R_ + r;
    maskp[idx] = sm;
    mask[lin] = sm;
#pragma unroll
    for (int k = 0; k < 9; k++) rots[(size_t)lin * 9 + k] = sr[k];
#pragma unroll
    for (int k = 0; k < 3; k++) trans[(size_t)lin * 3 + k] = st[k];
  } else {
    int p = idx - B_ * RP_;
    const int per = B_ * H_ * (RP_ - R_) * 4;
    if (p >= 3 * per) return;
    int a = p / per;
    int q = p % per;
    int bh = q / ((RP_ - R_) * 4);
    int rem = q % ((RP_ - R_) * 4);
    float* dst = (a == 0) ? Kt : (a == 1) ? PKt : Vt;
    dst[(size_t)bh * RP_ * 4 + (size_t)R_ * 4 + rem] = 0.f;
  }
}

// ---------------------------------------------------------------------------
// Rotate QKV fields; Q-side row-major, K/V-side [b][h][j][4] (xyz0 float4)
// ---------------------------------------------------------------------------
__global__ __launch_bounds__(128) void rotate_kernel(
    const float* __restrict__ qkv_raw, const float* __restrict__ rots,
    const float* __restrict__ trans, float* __restrict__ Qrow,
    float* __restrict__ PQrow, float* __restrict__ Kt,
    float* __restrict__ PKt, float* __restrict__ Vt) {
  const int blk = blockIdx.x;
  const int b = blk / R_;
  const int r = blk % R_;
  const int t = threadIdx.x;
  __shared__ float Rm[9], tr[3], raw[240];
  if (t < 9) Rm[t] = rots[(size_t)blk * 9 + t];
  if (t >= 9 && t < 12) tr[t - 9] = trans[(size_t)blk * 3 + (t - 9)];
  for (int i = t; i < 240; i += 128) raw[i] = qkv_raw[(size_t)blk * 240 + i];
  __syncthreads();
  if (t < 80) {
    int f = t / 16, h = t % 16;
    float x = raw[f * 48 + h * 3 + 0];
    float y = raw[f * 48 + h * 3 + 1];
    float z = raw[f * 48 + h * 3 + 2];
    float r0 = Rm[0] * x + Rm[1] * y + Rm[2] * z;
    float r1 = Rm[3] * x + Rm[4] * y + Rm[5] * z;
    float r2 = Rm[6] * x + Rm[7] * y + Rm[8] * z;
    if (f == 2 || f == 3) { r0 += tr[0]; r1 += tr[1]; r2 += tr[2]; }
    if (f == 0 || f == 2) {
      float* dst = (f == 0) ? Qrow : PQrow;
      size_t o = (size_t)blk * 48 + h * 3;
      dst[o] = r0; dst[o + 1] = r1; dst[o + 2] = r2;
    } else {
      float* dst = (f == 1) ? Kt : (f == 3) ? PKt : Vt;
      size_t base = ((size_t)(b * H_ + h) * RP_ + r) * 4;
      *(float4*)(dst + base) = make_float4(r0, r1, r2, 0.f);
    }
  }
}

// ---------------------------------------------------------------------------
// Attention: 256 thd / 4 waves, hh-loop (round-8 structure, measured 41.8us)
// + float4 K/Pk/V loads (1 dwordx4 instead of 3 dword gathers per array).
// Fused inverse-rotation + out-projection (transposed owT).
// ---------------------------------------------------------------------------
__global__ __launch_bounds__(256) void attn2_kernel(
    const float* __restrict__ Qrow, const float* __restrict__ PQrow,
    const float* __restrict__ Kt, const float* __restrict__ PKt,
    const float* __restrict__ Vt, const float* __restrict__ rots,
    const int* __restrict__ mask, const int* __restrict__ maskp,
    const float* __restrict__ rs, const float* __restrict__ ds,
    const float* __restrict__ owT, const float* __restrict__ out_b,
    float* __restrict__ emb) {
  const int blk = blockIdx.x;
  const int b = blk / (R_ / 2);
  const int ip = blk % (R_ / 2);
  const int i0 = ip * 2;
  const int t = threadIdx.x;
  const int lane = t & 63;
  const int w = t >> 6;

  __shared__ float qs[2][48], ps[2][48], og[2][48];
  __shared__ float crs[16], cds[16];
  __shared__ int mi[2];

  if (t < 96) {
    int io = t / 48, k2 = t % 48;
    int i = i0 + io;
    qs[io][k2] = Qrow[((size_t)(b * R_ + i)) * 48 + k2];
    ps[io][k2] = PQrow[((size_t)(b * R_ + i)) * 48 + k2];
  } else if (t < 112) {
    int h = t - 96;
    const float sc = 0.57735026918962576f;
    crs[h] = log1pf(expf(rs[h])) * sc;
    cds[h] = log1pf(expf(ds[h])) * sc;
  } else if (t < 114) {
    mi[t - 112] = mask[b * R_ + i0 + (t - 112)];
  }
  __syncthreads();

  float mb[8];
#pragma unroll
  for (int jb = 0; jb < 8; jb++) {
    int j = jb * 64 + lane;
    mb[jb] = maskp[b * RP_ + j] ? -1e9f : 0.f;
  }
  const float bi0 = mi[0] ? -1e9f : 0.f;
  const float bi1 = mi[1] ? -1e9f : 0.f;

  for (int hh = 0; hh < 4; hh++) {
    const int h = hh * 4 + w;
    const float sA = crs[h], sD = cds[h];
    const float qx0 = qs[0][h * 3], qy0 = qs[0][h * 3 + 1], qz0 = qs[0][h * 3 + 2];
    const float px0 = ps[0][h * 3], py0 = ps[0][h * 3 + 1], pz0 = ps[0][h * 3 + 2];
    const float qx1 = qs[1][h * 3], qy1 = qs[1][h * 3 + 1], qz1 = qs[1][h * 3 + 2];
    const float px1 = ps[1][h * 3], py1 = ps[1][h * 3 + 1], pz1 = ps[1][h * 3 + 2];
    const float4* kb4 = (const float4*)(Kt + ((size_t)(b * H_ + h) * RP_) * 4);
    const float4* pb4 = (const float4*)(PKt + ((size_t)(b * H_ + h) * RP_) * 4);
    const float4* vb4 = (const float4*)(Vt + ((size_t)(b * H_ + h) * RP_) * 4);

    float l0[8], l1[8];
    float m0 = -3e38f, m1 = -3e38f;
#pragma unroll
    for (int jb = 0; jb < 8; jb++) {
      int j = jb * 64 + lane;
      float4 k4 = kb4[j];
      float4 p4 = pb4[j];
      float dx0 = px0 - p4.x, dy0 = py0 - p4.y, dz0 = pz0 - p4.z;
      float d0 = sqrtf(dx0 * dx0 + dy0 * dy0 + dz0 * dz0);
      l0[jb] = (qx0 * k4.x + qy0 * k4.y + qz0 * k4.z) * sA - d0 * sD + mb[jb] + bi0;
      m0 = fmaxf(m0, l0[jb]);
      float dx1 = px1 - p4.x, dy1 = py1 - p4.y, dz1 = pz1 - p4.z;
      float d1 = sqrtf(dx1 * dx1 + dy1 * dy1 + dz1 * dz1);
      l1[jb] = (qx1 * k4.x + qy1 * k4.y + qz1 * k4.z) * sA - d1 * sD + mb[jb] + bi1;
      m1 = fmaxf(m1, l1[jb]);
    }
#pragma unroll
    for (int s = 1; s < 64; s <<= 1) {
      m0 = fmaxf(m0, __shfl_xor(m0, s));
      m1 = fmaxf(m1, __shfl_xor(m1, s));
    }
    float s0 = 0.f, s1 = 0.f;
    float ox0 = 0.f, oy0 = 0.f, oz0 = 0.f, ox1 = 0.f, oy1 = 0.f, oz1 = 0.f;
#pragma unroll
    for (int jb = 0; jb < 8; jb++) {
      int j = jb * 64 + lane;
      float p0 = expf(l0[jb] - m0);
      float p1 = expf(l1[jb] - m1);
      s0 += p0; s1 += p1;
      float4 v4 = vb4[j];
      ox0 += p0 * v4.x; oy0 += p0 * v4.y; oz0 += p0 * v4.z;
      ox1 += p1 * v4.x; oy1 += p1 * v4.y; oz1 += p1 * v4.z;
    }
#pragma unroll
    for (int s = 1; s < 64; s <<= 1) {
      s0 += __shfl_xor(s0, s); s1 += __shfl_xor(s1, s);
      ox0 += __shfl_xor(ox0, s); oy0 += __shfl_xor(oy0, s); oz0 += __shfl_xor(oz0, s);
      ox1 += __shfl_xor(ox1, s); oy1 += __shfl_xor(oy1, s); oz1 += __shfl_xor(oz1, s);
    }
    if (lane == 0) {
      og[0][h * 3] = ox0 / s0; og[0][h * 3 + 1] = oy0 / s0; og[0][h * 3 + 2] = oz0 / s0;
      og[1][h * 3] = ox1 / s1; og[1][h * 3 + 1] = oy1 / s1; og[1][h * 3 + 2] = oz1 / s1;
    }
  }
  __syncthreads();
  // inverse rotation in-place on og
  float r0v0 = 0.f, r0v1 = 0.f;
  if (t < 48) {
    int hh = t / 3, i3 = t % 3;
    const float* Rm0 = rots + ((size_t)(b * R_ + i0)) * 9;
    const float* Rm1 = rots + ((size_t)(b * R_ + i0 + 1)) * 9;
    r0v0 = Rm0[0 + i3] * og[0][hh * 3 + 0] + Rm0[3 + i3] * og[0][hh * 3 + 1] +
           Rm0[6 + i3] * og[0][hh * 3 + 2];
    r0v1 = Rm1[0 + i3] * og[1][hh * 3 + 0] + Rm1[3 + i3] * og[1][hh * 3 + 1] +
           Rm1[6 + i3] * og[1][hh * 3 + 2];
  }
  __syncthreads();
  if (t < 48) { og[0][t] = r0v0; og[1][t] = r0v1; }
  __syncthreads();
  // fused out-projection: coalesced owT[k][c] reads
#pragma unroll
  for (int io = 0; io < 2; io++) {
    float* erow = emb + ((size_t)(b * R_ + i0 + io)) * D_;
#pragma unroll
    for (int half = 0; half < 2; half++) {
      int c = half * 256 + t;
      float a0 = 0.f, a1 = 0.f, a2 = 0.f, a3 = 0.f;
#pragma unroll
      for (int k = 0; k < 48; k += 4) {
        a0 += og[io][k + 0] * owT[(size_t)(k + 0) * D_ + c];
        a1 += og[io][k + 1] * owT[(size_t)(k + 1) * D_ + c];
        a2 += og[io][k + 2] * owT[(size_t)(k + 2) * D_ + c];
        a3 += og[io][k + 3] * owT[(size_t)(k + 3) * D_ + c];
      }
      erow[c] += out_b[c] + ((a0 + a1) + (a2 + a3));
    }
  }
}

// ---------------------------------------------------------------------------
extern "C" void kernel_launch(void* const* d_in, const int* in_sizes, int n_in,
                              void* d_out, int out_size, void* d_ws, size_t ws_size,
                              hipStream_t stream) {
  const float* vh_x = (const float*)d_in[0];
  const float* vl_x = (const float*)d_in[1];
  const float* vh_rots = (const float*)d_in[2];
  const float* vh_trans = (const float*)d_in[3];
  const float* vl_rots = (const float*)d_in[4];
  const float* vl_trans = (const float*)d_in[5];
  const float* ep_feats = (const float*)d_in[6];
  const float* ep_rots = (const float*)d_in[7];
  const float* ep_trans = (const float*)d_in[8];
  const int* vh_mask = (const int*)d_in[9];
  const int* vl_mask = (const int*)d_in[10];
  const int* ep_mask = (const int*)d_in[11];
  const float* vh_emb_w = (const float*)d_in[12];
  const float* vl_emb_w = (const float*)d_in[13];
  const float* tgt_emb_w = (const float*)d_in[14];
  const float* qkv_w = (const float*)d_in[15];
  const float* out_w = (const float*)d_in[16];
  const float* out_b = (const float*)d_in[17];
  const float* ln_g = (const float*)d_in[18];
  const float* ln_b = (const float*)d_in[19];
  const float* r_scale = (const float*)d_in[20];
  const float* d_scale = (const float*)d_in[21];
  const float* ln2_g = (const float*)d_in[22];
  const float* ln2_b = (const float*)d_in[23];
  const float* w12 = (const float*)d_in[24];
  const float* w3 = (const float*)d_in[25];
  const float* out_vh_w = (const float*)d_in[26];
  const float* out_vh_gate_w = (const float*)d_in[27];
  const float* out_vh_gate_b = (const float*)d_in[28];
  const float* out_vl_w = (const float*)d_in[29];
  const float* out_vl_gate_w = (const float*)d_in[30];
  const float* out_vl_gate_b = (const float*)d_in[31];

  const int BR = B_ * R_;  // 2024

  // ---- workspace layout (256B-aligned) ----
  uint8_t* P = (uint8_t*)d_ws;
  auto alloc = [&](size_t bytes) {
    uint8_t* p = P;
    P += (bytes + 255) & ~(size_t)255;
    return p;
  };
  float* emb = (float*)alloc((size_t)BR * D_ * 4);
  _Float16* xnh = (_Float16*)alloc((size_t)BR * D_ * 2);
  float* qkvr = (float*)alloc((size_t)BR * 240 * 4);
  float* Qrow = (float*)alloc((size_t)BR * 48 * 4);
  float* PQrow = (float*)alloc((size_t)BR * 48 * 4);
  float* Kt = (float*)alloc((size_t)B_ * H_ * RP_ * 4 * 4);
  float* PKt = (float*)alloc((size_t)B_ * H_ * RP_ * 4 * 4);
  float* Vt = (float*)alloc((size_t)B_ * H_ * RP_ * 4 * 4);
  _Float16* ghalf = (_Float16*)alloc((size_t)BR * HID_ * 2);
  float* rots_c = (float*)alloc((size_t)BR * 9 * 4);
  float* trans_c = (float*)alloc((size_t)BR * 3 * 4);
  int* mask_c = (int*)alloc((size_t)BR * 4);
  int* maskp = (int*)alloc((size_t)B_ * RP_ * 4);
  float* owT = (float*)alloc((size_t)NL_ * 48 * D_ * 4);
  _Float16* embh = (_Float16*)alloc((size_t)BR * D_ * 2);
  _Float16* qkvh = (_Float16*)alloc((size_t)NL_ * 240 * D_ * 2);
  _Float16* w12h = (_Float16*)alloc((size_t)NL_ * 2 * HID_ * D_ * 2);
  _Float16* w3h = (_Float16*)alloc((size_t)NL_ * D_ * HID_ * 2);
  _Float16* vhxh = (_Float16*)alloc((size_t)B_ * VH_ * DIN_ * 2);
  _Float16* vlxh = (_Float16*)alloc((size_t)B_ * VL_ * DIN_ * 2);
  _Float16* eph = (_Float16*)alloc((size_t)B_ * EP_ * DEP_ * 2);
  _Float16* vhewh = (_Float16*)alloc((size_t)D_ * DIN_ * 2);
  _Float16* vlewh = (_Float16*)alloc((size_t)D_ * DIN_ * 2);
  _Float16* tgewh = (_Float16*)alloc((size_t)D_ * DEP_ * 2);
  _Float16* ovhw = (_Float16*)alloc((size_t)DIN_ * D_ * 2);
  _Float16* ovhgw = (_Float16*)alloc((size_t)DIN_ * D_ * 2);
  _Float16* ovlw = (_Float16*)alloc((size_t)DIN_ * D_ * 2);
  _Float16* ovlgw = (_Float16*)alloc((size_t)DIN_ * D_ * 2);

  // one multi-segment fp32->fp16 conversion (weights + inputs), 16-elem units
  {
    ThSegs sg;
    const float* srcs[13] = {qkv_w, w12, w3, vh_x, vl_x, ep_feats,
                             vh_emb_w, vl_emb_w, tgt_emb_w,
                             out_vh_w, out_vh_gate_w, out_vl_w, out_vl_gate_w};
    _Float16* dsts[13] = {qkvh, w12h, w3h, vhxh, vlxh, eph,
                          vhewh, vlewh, tgewh, ovhw, ovhgw, ovlw, ovlgw};
    int n16s[13] = {NL_ * 240 * D_ / 16, NL_ * 2 * HID_ * D_ / 16,
                    NL_ * D_ * HID_ / 16, B_ * VH_ * DIN_ / 16,
                    B_ * VL_ * DIN_ / 16, B_ * EP_ * DEP_ / 16,
                    D_ * DIN_ / 16, D_ * DIN_ / 16, D_ * DEP_ / 16,
                    DIN_ * D_ / 16, DIN_ * D_ / 16, DIN_ * D_ / 16,
                    DIN_ * D_ / 16};
    int c = 0;
    for (int i = 0; i < 13; i++) {
      sg.src[i] = srcs[i]; sg.dst[i] = dsts[i];
      sg.cum[i] = c; c += n16s[i];
    }
    sg.cum[13] = c;
    tohalf_multi_kernel<<<2048, 256, 0, stream>>>(sg);
  }

  // transpose out_w for the attn epilogue (once per call)
  {
    int total = NL_ * 48 * D_;
    transpose_ow_kernel<<<(total + 255) / 256, 256, 0, stream>>>(out_w, owT);
  }

  // prep: concat + padded mask + K/V pad zero
  {
    int total = B_ * RP_ + 3 * B_ * H_ * (RP_ - R_) * 4;
    prep_kernel<<<(total + 255) / 256, 256, 0, stream>>>(
        vh_rots, vh_trans, vl_rots, vl_trans, ep_rots, ep_trans, vh_mask,
        vl_mask, ep_mask, rots_c, trans_c, mask_c, maskp, Kt, PKt, Vt);
  }

  auto gemm16b = [&](const _Float16* A, const _Float16* W, float* C,
                     const float* bias, int M, int N, int K, int mode,
                     int crpb, int cR, int cbase, int pe) {
    int nbm = (M + 63) / 64, nbn = (N + 63) / 64;
    gemm16b_kernel<<<nbm * nbn, 256, 0, stream>>>(A, W, C, bias, M, N, K, mode,
                                                  crpb, cR, cbase, pe);
  };

  // embeddings (fp16 MFMA, fused PE, remapped into emb)
  gemm16b(vhxh, vhewh, emb, nullptr, B_ * VH_, D_, DIN_, MODE_STORE,
          VH_, R_, 0, 1);
  gemm16b(vlxh, vlewh, emb, nullptr, B_ * VL_, D_, DIN_, MODE_STORE,
          VL_, R_, VH_, 1);
  gemm16b(eph, tgewh, emb, nullptr, B_ * EP_, D_, DEP_, MODE_STORE,
          EP_, R_, VH_ + VL_, 0);

  for (int l = 0; l < NL_; l++) {
    const _Float16* qwh = qkvh + (size_t)l * 240 * D_;
    const float* owTl = owT + (size_t)l * 48 * D_;
    const float* obias = out_b + (size_t)l * D_;
    const float* lg = ln_g + (size_t)l * D_;
    const float* lb = ln_b + (size_t)l * D_;
    const float* l2g = ln2_g + (size_t)l * D_;
    const float* l2b = ln2_b + (size_t)l * D_;
    const float* rs = r_scale + (size_t)l * H_;
    const float* dsc = d_scale + (size_t)l * H_;
    const _Float16* w12ah = w12h + (size_t)l * 2 * HID_ * D_;
    const _Float16* w12bh = w12ah + (size_t)HID_ * D_;
    const _Float16* w3lh = w3h + (size_t)l * D_ * HID_;

    // attention (out-projection fused into attn2, transposed weights)
    ln_kernel<<<BR, 256, 0, stream>>>(emb, lg, lb, xnh);
    gemm16b(xnh, qwh, qkvr, nullptr, BR, 240, D_, MODE_STORE, BR, BR, 0, 0);
    rotate_kernel<<<BR, 128, 0, stream>>>(qkvr, rots_c, trans_c, Qrow, PQrow,
                                          Kt, PKt, Vt);
    attn2_kernel<<<B_ * (R_ / 2), 256, 0, stream>>>(
        Qrow, PQrow, Kt, PKt, Vt, rots_c, mask_c, maskp, rs, dsc, owTl, obias,
        emb);

    // swiglu
    ln_kernel<<<BR, 256, 0, stream>>>(emb, l2g, l2b, xnh);
    {
      int nbm = (BR + 127) / 128, nbn = HID_ / 64;
      gemm16sw_kernel<<<nbm * nbn, 256, 0, stream>>>(xnh, w12ah, w12bh, ghalf,
                                                     BR, D_);
    }
    gemm16b(ghalf, w3lh, emb, nullptr, BR, D_, HID_, MODE_ADD_BIAS,
            BR, BR, 0, 0);
  }

  // output heads: emb -> fp16, then fused dual-GEMM + gate -> d_out
  tohalf_kernel<<<1024, 256, 0, stream>>>(emb, embh, BR * D_ / 8);
  {
    int M = B_ * VH_;
    int nbm = (M + 63) / 64;
    gemm16gate_kernel<<<nbm * 4, 256, 0, stream>>>(
        embh, ovhw, ovhgw, vh_x, out_vh_gate_b, vh_mask, (float*)d_out, M, D_,
        VH_, R_, 0);
  }
  {
    int M = B_ * VL_;
    int nbm = (M + 63) / 64;
    gemm16gate_kernel<<<nbm * 4, 256, 0, stream>>>(
        embh, ovlw, ovlgw, vl_x, out_vl_gate_b, vl_mask,
        (float*)d_out + (size_t)B_ * VH_ * DIN_, M, D_, VL_, R_, VH_);
  }
}